// Round 6
// baseline (57.465 us; speedup 1.0000x reference)
//
#include <hip/hip_runtime.h>
#include <math.h>

#define HW 256
#define TW 64
#define TH 32
#define LW 68           // 2 halo + 64 + 2 halo (272B row stride, 16B-aligned)
#define LH 36           // 2 halo + 32 + 2 halo
#define NT 4            // tiles chained per block (vertical)

__device__ __forceinline__ int reflect_idx(int i) {
    i = (i < 0) ? -i : i;
    i = (i >= HW) ? (2 * HW - 2 - i) : i;
    return i;
}

__device__ __forceinline__ float4 max4(float4 a, float4 b) {
    float4 r; r.x = fmaxf(a.x, b.x); r.y = fmaxf(a.y, b.y);
    r.z = fmaxf(a.z, b.z); r.w = fmaxf(a.w, b.w); return r;
}
__device__ __forceinline__ float4 max34(float4 a, float4 b, float4 c) {
    float4 r; r.x = fmaxf(fmaxf(a.x, b.x), c.x); r.y = fmaxf(fmaxf(a.y, b.y), c.y);
    r.z = fmaxf(fmaxf(a.z, b.z), c.z); r.w = fmaxf(fmaxf(a.w, b.w), c.w); return r;
}
__device__ __forceinline__ float4 add4(float4 a, float4 b) {
    float4 r; r.x = a.x + b.x; r.y = a.y + b.y;
    r.z = a.z + b.z; r.w = a.w + b.w; return r;
}
__device__ __forceinline__ float4 sub4(float4 a, float4 b) {
    float4 r; r.x = a.x - b.x; r.y = a.y - b.y;
    r.z = a.z - b.z; r.w = a.w - b.w; return r;
}

// One output row, 4 pixels. Window rows A0..B4 (A=cols0-3, B=cols4-7),
// column maxes cm, column sums cs. bp = beta*log2e; c04b = 0.04*bp.
__device__ __forceinline__ void proc_row(
    float4 A0, float4 B0, float4 A1, float4 B1, float4 A2, float4 B2,
    float4 A3, float4 B3, float4 A4, float4 B4,
    float4 cmA, float4 cmB, float4 csA, float4 csB,
    float bp, float c04b, float inv_bp, float lam,
    float* __restrict__ orow)
{
    const float cs[8] = {csA.x,csA.y,csA.z,csA.w, csB.x,csB.y,csB.z,csB.w};
    const float cm[8] = {cmA.x,cmA.y,cmA.z,cmA.w, cmB.x,cmB.y,cmB.z,cmB.w};
    const float vv[5][8] = {
        {A0.x,A0.y,A0.z,A0.w, B0.x,B0.y,B0.z,B0.w},
        {A1.x,A1.y,A1.z,A1.w, B1.x,B1.y,B1.z,B1.w},
        {A2.x,A2.y,A2.z,A2.w, B2.x,B2.y,B2.z,B2.w},
        {A3.x,A3.y,A3.z,A3.w, B3.x,B3.y,B3.z,B3.w},
        {A4.x,A4.y,A4.z,A4.w, B4.x,B4.y,B4.z,B4.w}};

    // Sliding horizontal sums of the 8 column sums (5-wide windows)
    const float t12 = cs[1] + cs[2];
    const float t34 = cs[3] + cs[4];
    const float t56 = cs[5] + cs[6];
    const float u   = t12 + t34;
    const float w_  = t34 + t56;
    const float S[4] = {cs[0] + u, u + cs[5], cs[2] + w_, w_ + cs[7]};

    // Horizontal max of 5 column-maxes with shared pairs (v_max3 fusion)
    const float h12 = fmaxf(cm[1], cm[2]);
    const float h34 = fmaxf(cm[3], cm[4]);
    const float h56 = fmaxf(cm[5], cm[6]);
    const float m[4] = {fmaxf(fmaxf(cm[0], h12), h34),
                        fmaxf(fmaxf(h12, h34), cm[5]),
                        fmaxf(fmaxf(cm[2], h34), h56),
                        fmaxf(fmaxf(h34, h56), cm[7])};

    float bm[4], ws[4], wa[4];
    #pragma unroll
    for (int p = 0; p < 4; ++p) { bm[p] = S[p] * c04b; ws[p] = 0.0f; wa[p] = 0.0f; }

    #pragma unroll
    for (int k = 0; k < 5; ++k) {
        #pragma unroll
        for (int j = 0; j < 5; ++j) {
            #pragma unroll
            for (int p = 0; p < 4; ++p) {
                const float tv = fmaf(bp, vv[k][p + j], -bm[p]);     // beta'*(v-mean)
                const float e  = __builtin_amdgcn_exp2f(-fabsf(tv)); // src-mod -|t|
                ws[p] += e;
                wa[p] = fmaf(e, tv, wa[p]);
            }
        }
    }

    float o[4];
    #pragma unroll
    for (int p = 0; p < 4; ++p) {
        const float mean = S[p] * 0.04f;
        const float med  = fmaf(wa[p] * __builtin_amdgcn_rcpf(ws[p]), inv_bp, mean);
        o[p] = fmaf(lam, med - m[p], m[p]);
    }
    float4 o4; o4.x = o[0]; o4.y = o[1]; o4.z = o[2]; o4.w = o[3];
    *(float4*)orow = o4;
}

// Load one tile's (LH x TW+4) staging data into registers (reflect applied).
__device__ __forceinline__ void stage_regs(
    const float* __restrict__ xp, int ty0, int tx0, int tid,
    float pm[9], float& ph)
{
    const int c   = tid & 63;
    const int r0s = tid >> 6;            // 0..3
    const int gx  = tx0 + c;
    #pragma unroll
    for (int k = 0; k < 9; ++k) {
        const int r  = r0s + 4 * k;      // 0..35
        const int gy = reflect_idx(ty0 + r - 2);
        pm[k] = xp[gy * HW + gx];
    }
    if (tid < 144) {                     // cols {0,1,66,67} x 36 rows
        const int jj = tid & 3;
        const int j  = (jj < 2) ? jj : (64 + jj);
        const int r  = tid >> 2;         // 0..35
        ph = xp[reflect_idx(ty0 + r - 2) * HW + reflect_idx(tx0 + j - 2)];
    }
}

__device__ __forceinline__ void write_lds(
    float* __restrict__ buf, int tid, const float pm[9], float ph)
{
    const int c   = tid & 63;
    const int r0s = tid >> 6;
    #pragma unroll
    for (int k = 0; k < 9; ++k)
        buf[(r0s + 4 * k) * LW + c + 2] = pm[k];
    if (tid < 144) {
        const int jj = tid & 3;
        const int j  = (jj < 2) ? jj : (64 + jj);
        buf[(tid >> 2) * LW + j] = ph;
    }
}

__global__ __launch_bounds__(256, 4)
void maxmedian_kernel(const float* __restrict__ x,
                      const float* __restrict__ mix,
                      const float* __restrict__ beta_raw,
                      float* __restrict__ out,
                      int C) {
    __shared__ __align__(16) float buf[2][LH * LW];   // 19.6 KB double buffer

    // chain id -> plane, column strip, vertical half
    const int plane   = blockIdx.x >> 3;
    const int rem     = blockIdx.x & 7;
    const int tx0     = (rem >> 1) * TW;       // 0,64,128,192
    const int ty_base = (rem & 1) * (NT * TH); // 0 or 128

    const float* __restrict__ xp = x + (size_t)plane * (HW * HW);
    const int tid = threadIdx.x;

    // ---- Parameters ----
    const int ch = plane % C;
    const float lam  = 1.0f / (1.0f + __expf(-mix[ch]));
    const float beta = 5.0f + 45.0f / (1.0f + __expf(-beta_raw[0]));
    const float bp     = beta * 1.44269504088896f;   // beta * log2(e) > 0
    const float inv_bp = 1.0f / bp;
    const float c04b   = 0.04f * bp;

    // ---- Thread's compute mapping (R3 structure: 2 rows x 4 cols) ----
    const int tx  = tid & 15;
    const int ryq = tid >> 4;        // 0..15
    const int r0  = ryq * 2;

    float pm[9];
    float ph = 0.0f;

    // Prologue: stage tile 0
    stage_regs(xp, ty_base, tx0, tid, pm, ph);
    write_lds(buf[0], tid, pm, ph);
    __syncthreads();

    #pragma unroll 1
    for (int t = 0; t < NT; ++t) {
        const int ty0 = ty_base + t * TH;

        // Issue next tile's global loads early (land under this tile's math)
        if (t < NT - 1)
            stage_regs(xp, ty0 + TH, tx0, tid, pm, ph);

        // ---- Compute current tile from LDS ----
        const float* lbase = &buf[t & 1][r0 * LW + 4 * tx];

        float4 w0a = *(const float4*)(lbase + 0 * LW);
        float4 w0b = *(const float4*)(lbase + 0 * LW + 4);
        float4 w1a = *(const float4*)(lbase + 1 * LW);
        float4 w1b = *(const float4*)(lbase + 1 * LW + 4);
        float4 w2a = *(const float4*)(lbase + 2 * LW);
        float4 w2b = *(const float4*)(lbase + 2 * LW + 4);
        float4 w3a = *(const float4*)(lbase + 3 * LW);
        float4 w3b = *(const float4*)(lbase + 3 * LW + 4);
        float4 w4a = *(const float4*)(lbase + 4 * LW);
        float4 w4b = *(const float4*)(lbase + 4 * LW + 4);
        float4 w5a = *(const float4*)(lbase + 5 * LW);
        float4 w5b = *(const float4*)(lbase + 5 * LW + 4);

        float4 csA = add4(add4(add4(w0a, w1a), add4(w2a, w3a)), w4a);
        float4 csB = add4(add4(add4(w0b, w1b), add4(w2b, w3b)), w4b);

        const float4 p12a = max4(w1a, w2a), p12b = max4(w1b, w2b);
        const float4 p34a = max4(w3a, w4a), p34b = max4(w3b, w4b);
        const float4 cm0a = max34(w0a, p12a, p34a);
        const float4 cm0b = max34(w0b, p12b, p34b);

        float* __restrict__ orow =
            out + (size_t)plane * (HW * HW) + (size_t)(ty0 + r0) * HW + (tx0 + 4 * tx);

        proc_row(w0a,w0b, w1a,w1b, w2a,w2b, w3a,w3b, w4a,w4b,
                 cm0a, cm0b, csA, csB, bp, c04b, inv_bp, lam, orow);

        csA = add4(csA, sub4(w5a, w0a));
        csB = add4(csB, sub4(w5b, w0b));
        const float4 cm1a = max34(p12a, p34a, w5a);
        const float4 cm1b = max34(p12b, p34b, w5b);

        proc_row(w1a,w1b, w2a,w2b, w3a,w3b, w4a,w4b, w5a,w5b,
                 cm1a, cm1b, csA, csB, bp, c04b, inv_bp, lam, orow + HW);

        // ---- Write prefetched tile to the other buffer, flip ----
        if (t < NT - 1) {
            write_lds(buf[(t + 1) & 1], tid, pm, ph);
            __syncthreads();
        }
    }
}

extern "C" void kernel_launch(void* const* d_in, const int* in_sizes, int n_in,
                              void* d_out, int out_size, void* d_ws, size_t ws_size,
                              hipStream_t stream) {
    const float* x        = (const float*)d_in[0];
    const float* mix      = (const float*)d_in[1];
    const float* beta_raw = (const float*)d_in[2];
    float* out            = (float*)d_out;

    const int planes = in_sizes[0] / (HW * HW);     // B*C = 128
    const int C      = in_sizes[1];                 // 32
    // 8 chains per plane: 4 column strips x 2 vertical halves (4 tiles each)
    const int grid = planes * 8;                    // 1024 = 256 CUs x 4 blocks

    maxmedian_kernel<<<grid, 256, 0, stream>>>(x, mix, beta_raw, out, C);
}

// Round 7
// 44.481 us; speedup vs baseline: 1.2919x; 1.2919x over previous
//
#include <hip/hip_runtime.h>
#include <math.h>

#define HW 256
#define TW 64
#define TH 32
#define LW 68           // 2 halo + 64 + 2 halo
#define LH 36           // 2 halo + 32 + 2 halo

// Schraudolph exp2: 2^x ~= bits(u32((x + 127 - sigma) * 2^23)), x <= 0.
// sigma = 0.0354 balances max relative error to ~+-3.6%.
#define EXP2_C23 8388608.0f                 // 2^23
#define EXP2_B   1065056256.0f              // (127 - 0.0354) * 2^23, rounded

__device__ __forceinline__ int reflect_idx(int i) {
    i = (i < 0) ? -i : i;
    i = (i >= HW) ? (2 * HW - 2 - i) : i;
    return i;
}

__device__ __forceinline__ float4 max4(float4 a, float4 b) {
    float4 r; r.x = fmaxf(a.x, b.x); r.y = fmaxf(a.y, b.y);
    r.z = fmaxf(a.z, b.z); r.w = fmaxf(a.w, b.w); return r;
}
__device__ __forceinline__ float4 max34(float4 a, float4 b, float4 c) {
    float4 r; r.x = fmaxf(fmaxf(a.x, b.x), c.x); r.y = fmaxf(fmaxf(a.y, b.y), c.y);
    r.z = fmaxf(fmaxf(a.z, b.z), c.z); r.w = fmaxf(fmaxf(a.w, b.w), c.w); return r;
}
__device__ __forceinline__ float4 add4(float4 a, float4 b) {
    float4 r; r.x = a.x + b.x; r.y = a.y + b.y;
    r.z = a.z + b.z; r.w = a.w + b.w; return r;
}
__device__ __forceinline__ float4 sub4(float4 a, float4 b) {
    float4 r; r.x = a.x - b.x; r.y = a.y - b.y;
    r.z = a.z - b.z; r.w = a.w - b.w; return r;
}

// One output row, 4 pixels. Window rows A0..B4 (A=cols0-3, B=cols4-7),
// column maxes cm, column sums cs. bp = beta*log2e; c04b = 0.04*bp.
__device__ __forceinline__ void proc_row(
    float4 A0, float4 B0, float4 A1, float4 B1, float4 A2, float4 B2,
    float4 A3, float4 B3, float4 A4, float4 B4,
    float4 cmA, float4 cmB, float4 csA, float4 csB,
    float bp, float c04b, float inv_bp, float lam,
    float* __restrict__ orow)
{
    const float cs[8] = {csA.x,csA.y,csA.z,csA.w, csB.x,csB.y,csB.z,csB.w};
    const float cm[8] = {cmA.x,cmA.y,cmA.z,cmA.w, cmB.x,cmB.y,cmB.z,cmB.w};
    const float vv[5][8] = {
        {A0.x,A0.y,A0.z,A0.w, B0.x,B0.y,B0.z,B0.w},
        {A1.x,A1.y,A1.z,A1.w, B1.x,B1.y,B1.z,B1.w},
        {A2.x,A2.y,A2.z,A2.w, B2.x,B2.y,B2.z,B2.w},
        {A3.x,A3.y,A3.z,A3.w, B3.x,B3.y,B3.z,B3.w},
        {A4.x,A4.y,A4.z,A4.w, B4.x,B4.y,B4.z,B4.w}};

    // Sliding horizontal sums of the 8 column sums (5-wide windows)
    const float t12 = cs[1] + cs[2];
    const float t34 = cs[3] + cs[4];
    const float t56 = cs[5] + cs[6];
    const float u   = t12 + t34;
    const float w_  = t34 + t56;
    const float S[4] = {cs[0] + u, u + cs[5], cs[2] + w_, w_ + cs[7]};

    // Horizontal max of 5 column-maxes with shared pairs (v_max3 fusion)
    const float h12 = fmaxf(cm[1], cm[2]);
    const float h34 = fmaxf(cm[3], cm[4]);
    const float h56 = fmaxf(cm[5], cm[6]);
    const float m[4] = {fmaxf(fmaxf(cm[0], h12), h34),
                        fmaxf(fmaxf(h12, h34), cm[5]),
                        fmaxf(fmaxf(cm[2], h34), h56),
                        fmaxf(fmaxf(h34, h56), cm[7])};

    float bm[4], ws[4], wa[4];
    #pragma unroll
    for (int p = 0; p < 4; ++p) { bm[p] = S[p] * c04b; ws[p] = 0.0f; wa[p] = 0.0f; }

    #pragma unroll
    for (int k = 0; k < 5; ++k) {
        #pragma unroll
        for (int j = 0; j < 5; ++j) {
            #pragma unroll
            for (int p = 0; p < 4; ++p) {
                const float tv = fmaf(bp, vv[k][p + j], -bm[p]);    // beta'*(v-mean)
                // Schraudolph 2^(-|tv|): fma with -abs source modifier,
                // hardware-clamped float->uint (negative -> 0 -> e = 0.0f).
                const float uu = fmaf(-fabsf(tv), EXP2_C23, EXP2_B);
                const unsigned int ui = __float2uint_rz(uu);
                const float e = __uint_as_float(ui);
                ws[p] += e;
                wa[p] = fmaf(e, tv, wa[p]);
            }
        }
    }

    float o[4];
    #pragma unroll
    for (int p = 0; p < 4; ++p) {
        const float mean = S[p] * 0.04f;
        const float med  = fmaf(wa[p] * __builtin_amdgcn_rcpf(ws[p]), inv_bp, mean);
        o[p] = fmaf(lam, med - m[p], m[p]);
    }
    float4 o4; o4.x = o[0]; o4.y = o[1]; o4.z = o[2]; o4.w = o[3];
    *(float4*)orow = o4;
}

__global__ __launch_bounds__(256, 4)
void maxmedian_kernel(const float* __restrict__ x,
                      const float* __restrict__ mix,
                      const float* __restrict__ beta_raw,
                      float* __restrict__ out,
                      int C) {
    __shared__ __align__(16) float tile[LH * LW];

    const int tiles_x = HW / TW;                       // 4
    const int tiles_per_plane = tiles_x * (HW / TH);   // 32
    const int plane = blockIdx.x / tiles_per_plane;
    const int t     = blockIdx.x % tiles_per_plane;
    const int ty0 = (t / tiles_x) * TH;
    const int tx0 = (t % tiles_x) * TW;

    const float* __restrict__ xp = x + (size_t)plane * (HW * HW);
    const int tid = threadIdx.x;

    // ---- Stage (TH+4) x (TW+4) with reflect padding ----
    {
        const int c   = tid & 63;
        const int r0s = tid >> 6;             // 0..3
        const int gx  = tx0 + c;
        #pragma unroll
        for (int k = 0; k < 9; ++k) {
            const int r  = r0s + 4 * k;       // 0..35
            const int gy = reflect_idx(ty0 + r - 2);
            tile[r * LW + c + 2] = xp[gy * HW + gx];
        }
        if (tid < 144) {                      // cols {0,1,66,67} x 36 rows
            const int jj = tid & 3;
            const int j  = (jj < 2) ? jj : (64 + jj);
            const int r  = tid >> 2;
            const int gx2 = reflect_idx(tx0 + j - 2);
            const int gy2 = reflect_idx(ty0 + r - 2);
            tile[r * LW + j] = xp[gy2 * HW + gx2];
        }
    }
    __syncthreads();

    // ---- Parameters ----
    const int ch = plane % C;
    const float lam  = 1.0f / (1.0f + __expf(-mix[ch]));
    const float beta = 5.0f + 45.0f / (1.0f + __expf(-beta_raw[0]));
    const float bp     = beta * 1.44269504088896f;   // beta * log2(e) > 0
    const float inv_bp = 1.0f / bp;
    const float c04b   = 0.04f * bp;

    // ---- Each thread: 4-wide x 2-tall ----
    const int tx  = tid & 15;
    const int ryq = tid >> 4;        // 0..15
    const int r0  = ryq * 2;
    const float* lbase = &tile[r0 * LW + 4 * tx];

    float4 w0a = *(const float4*)(lbase + 0 * LW);
    float4 w0b = *(const float4*)(lbase + 0 * LW + 4);
    float4 w1a = *(const float4*)(lbase + 1 * LW);
    float4 w1b = *(const float4*)(lbase + 1 * LW + 4);
    float4 w2a = *(const float4*)(lbase + 2 * LW);
    float4 w2b = *(const float4*)(lbase + 2 * LW + 4);
    float4 w3a = *(const float4*)(lbase + 3 * LW);
    float4 w3b = *(const float4*)(lbase + 3 * LW + 4);
    float4 w4a = *(const float4*)(lbase + 4 * LW);
    float4 w4b = *(const float4*)(lbase + 4 * LW + 4);
    float4 w5a = *(const float4*)(lbase + 5 * LW);
    float4 w5b = *(const float4*)(lbase + 5 * LW + 4);

    float4 csA = add4(add4(add4(w0a, w1a), add4(w2a, w3a)), w4a);
    float4 csB = add4(add4(add4(w0b, w1b), add4(w2b, w3b)), w4b);

    const float4 p12a = max4(w1a, w2a), p12b = max4(w1b, w2b);
    const float4 p34a = max4(w3a, w4a), p34b = max4(w3b, w4b);
    const float4 cm0a = max34(w0a, p12a, p34a);
    const float4 cm0b = max34(w0b, p12b, p34b);

    float* __restrict__ orow =
        out + (size_t)plane * (HW * HW) + (size_t)(ty0 + r0) * HW + (tx0 + 4 * tx);

    proc_row(w0a,w0b, w1a,w1b, w2a,w2b, w3a,w3b, w4a,w4b,
             cm0a, cm0b, csA, csB, bp, c04b, inv_bp, lam, orow);

    csA = add4(csA, sub4(w5a, w0a));
    csB = add4(csB, sub4(w5b, w0b));
    const float4 cm1a = max34(p12a, p34a, w5a);
    const float4 cm1b = max34(p12b, p34b, w5b);

    proc_row(w1a,w1b, w2a,w2b, w3a,w3b, w4a,w4b, w5a,w5b,
             cm1a, cm1b, csA, csB, bp, c04b, inv_bp, lam, orow + HW);
}

extern "C" void kernel_launch(void* const* d_in, const int* in_sizes, int n_in,
                              void* d_out, int out_size, void* d_ws, size_t ws_size,
                              hipStream_t stream) {
    const float* x        = (const float*)d_in[0];
    const float* mix      = (const float*)d_in[1];
    const float* beta_raw = (const float*)d_in[2];
    float* out            = (float*)d_out;

    const int planes = in_sizes[0] / (HW * HW);                 // 128
    const int C      = in_sizes[1];                             // 32
    const int tiles_per_plane = (HW / TW) * (HW / TH);          // 32
    const int grid = planes * tiles_per_plane;                  // 4096

    maxmedian_kernel<<<grid, 256, 0, stream>>>(x, mix, beta_raw, out, C);
}

// Round 8
// 39.575 us; speedup vs baseline: 1.4520x; 1.1240x over previous
//
#include <hip/hip_runtime.h>
#include <math.h>

#define HW 256
#define TW 64
#define TH 16
#define LW 68           // 2 halo + 64 + 2 halo (272B row stride, 16B-aligned)
#define LH 20           // 2 halo + 16 + 2 halo

__device__ __forceinline__ int reflect_idx(int i) {
    i = (i < 0) ? -i : i;
    i = (i >= HW) ? (2 * HW - 2 - i) : i;
    return i;
}

__device__ __forceinline__ float4 max4(float4 a, float4 b) {
    float4 r; r.x = fmaxf(a.x, b.x); r.y = fmaxf(a.y, b.y);
    r.z = fmaxf(a.z, b.z); r.w = fmaxf(a.w, b.w); return r;
}
__device__ __forceinline__ float4 max34(float4 a, float4 b, float4 c) {
    float4 r; r.x = fmaxf(fmaxf(a.x, b.x), c.x); r.y = fmaxf(fmaxf(a.y, b.y), c.y);
    r.z = fmaxf(fmaxf(a.z, b.z), c.z); r.w = fmaxf(fmaxf(a.w, b.w), c.w); return r;
}
__device__ __forceinline__ float4 add4(float4 a, float4 b) {
    float4 r; r.x = a.x + b.x; r.y = a.y + b.y;
    r.z = a.z + b.z; r.w = a.w + b.w; return r;
}
__device__ __forceinline__ float4 sub4(float4 a, float4 b) {
    float4 r; r.x = a.x - b.x; r.y = a.y - b.y;
    r.z = a.z - b.z; r.w = a.w - b.w; return r;
}

// One output row, 4 pixels. Window rows A0..B4 (A=cols0-3, B=cols4-7),
// column maxes cm, column sums cs. bp = beta*log2e; c04b = 0.04*bp.
__device__ __forceinline__ void proc_row(
    float4 A0, float4 B0, float4 A1, float4 B1, float4 A2, float4 B2,
    float4 A3, float4 B3, float4 A4, float4 B4,
    float4 cmA, float4 cmB, float4 csA, float4 csB,
    float bp, float c04b, float inv_bp, float lam,
    float* __restrict__ orow)
{
    const float cs[8] = {csA.x,csA.y,csA.z,csA.w, csB.x,csB.y,csB.z,csB.w};
    const float cm[8] = {cmA.x,cmA.y,cmA.z,cmA.w, cmB.x,cmB.y,cmB.z,cmB.w};
    const float vv[5][8] = {
        {A0.x,A0.y,A0.z,A0.w, B0.x,B0.y,B0.z,B0.w},
        {A1.x,A1.y,A1.z,A1.w, B1.x,B1.y,B1.z,B1.w},
        {A2.x,A2.y,A2.z,A2.w, B2.x,B2.y,B2.z,B2.w},
        {A3.x,A3.y,A3.z,A3.w, B3.x,B3.y,B3.z,B3.w},
        {A4.x,A4.y,A4.z,A4.w, B4.x,B4.y,B4.z,B4.w}};

    // Sliding horizontal sums of the 8 column sums (5-wide windows)
    const float t12 = cs[1] + cs[2];
    const float t34 = cs[3] + cs[4];
    const float t56 = cs[5] + cs[6];
    const float u   = t12 + t34;
    const float w_  = t34 + t56;
    const float S[4] = {cs[0] + u, u + cs[5], cs[2] + w_, w_ + cs[7]};

    // Horizontal max of 5 column-maxes with shared pairs (v_max3 fusion)
    const float h12 = fmaxf(cm[1], cm[2]);
    const float h34 = fmaxf(cm[3], cm[4]);
    const float h56 = fmaxf(cm[5], cm[6]);
    const float m[4] = {fmaxf(fmaxf(cm[0], h12), h34),
                        fmaxf(fmaxf(h12, h34), cm[5]),
                        fmaxf(fmaxf(cm[2], h34), h56),
                        fmaxf(fmaxf(h34, h56), cm[7])};

    float bm[4], ws[4], wa[4];
    #pragma unroll
    for (int p = 0; p < 4; ++p) { bm[p] = S[p] * c04b; ws[p] = 0.0f; wa[p] = 0.0f; }

    #pragma unroll
    for (int k = 0; k < 5; ++k) {
        #pragma unroll
        for (int j = 0; j < 5; ++j) {
            #pragma unroll
            for (int p = 0; p < 4; ++p) {
                const float tv = fmaf(bp, vv[k][p + j], -bm[p]);     // beta'*(v-mean)
                const float e  = __builtin_amdgcn_exp2f(-fabsf(tv)); // src-mod -|t|
                ws[p] += e;
                wa[p] = fmaf(e, tv, wa[p]);
            }
        }
    }

    float o[4];
    #pragma unroll
    for (int p = 0; p < 4; ++p) {
        const float mean = S[p] * 0.04f;
        const float med  = fmaf(wa[p] * __builtin_amdgcn_rcpf(ws[p]), inv_bp, mean);
        o[p] = fmaf(lam, med - m[p], m[p]);
    }
    float4 o4; o4.x = o[0]; o4.y = o[1]; o4.z = o[2]; o4.w = o[3];
    *(float4*)orow = o4;
}

__global__ __launch_bounds__(128, 4)
void maxmedian_kernel(const float* __restrict__ x,
                      const float* __restrict__ mix,
                      const float* __restrict__ beta_raw,
                      float* __restrict__ out,
                      int C) {
    __shared__ __align__(16) float tile[LH * LW];

    const int tiles_x = HW / TW;                       // 4
    const int tiles_per_plane = tiles_x * (HW / TH);   // 64
    const int plane = blockIdx.x / tiles_per_plane;
    const int t     = blockIdx.x % tiles_per_plane;
    const int ty0 = (t / tiles_x) * TH;
    const int tx0 = (t % tiles_x) * TW;

    const float* __restrict__ xp = x + (size_t)plane * (HW * HW);
    const int tid = threadIdx.x;

    // ---- Stage (TH+4) x (TW+4) with reflect padding ----
    {
        const int c   = tid & 63;
        const int r0s = tid >> 6;             // 0..1
        const int gx  = tx0 + c;
        #pragma unroll
        for (int k = 0; k < 10; ++k) {
            const int r  = r0s + 2 * k;       // 0..19
            const int gy = reflect_idx(ty0 + r - 2);
            tile[r * LW + c + 2] = xp[gy * HW + gx];
        }
        if (tid < 80) {                       // cols {0,1,66,67} x 20 rows
            const int jj = tid & 3;
            const int j  = (jj < 2) ? jj : (64 + jj);
            const int r  = tid >> 2;          // 0..19
            const int gx2 = reflect_idx(tx0 + j - 2);
            const int gy2 = reflect_idx(ty0 + r - 2);
            tile[r * LW + j] = xp[gy2 * HW + gx2];
        }
    }
    __syncthreads();

    // ---- Parameters ----
    const int ch = plane % C;
    const float lam  = 1.0f / (1.0f + __expf(-mix[ch]));
    const float beta = 5.0f + 45.0f / (1.0f + __expf(-beta_raw[0]));
    const float bp     = beta * 1.44269504088896f;   // beta * log2(e) > 0
    const float inv_bp = 1.0f / bp;
    const float c04b   = 0.04f * bp;

    // ---- Each thread: 4-wide x 2-tall ----
    const int tx  = tid & 15;        // 16 column groups
    const int ryq = tid >> 4;        // 0..7
    const int r0  = ryq * 2;         // 0,2,...,14
    const float* lbase = &tile[r0 * LW + 4 * tx];

    float4 w0a = *(const float4*)(lbase + 0 * LW);
    float4 w0b = *(const float4*)(lbase + 0 * LW + 4);
    float4 w1a = *(const float4*)(lbase + 1 * LW);
    float4 w1b = *(const float4*)(lbase + 1 * LW + 4);
    float4 w2a = *(const float4*)(lbase + 2 * LW);
    float4 w2b = *(const float4*)(lbase + 2 * LW + 4);
    float4 w3a = *(const float4*)(lbase + 3 * LW);
    float4 w3b = *(const float4*)(lbase + 3 * LW + 4);
    float4 w4a = *(const float4*)(lbase + 4 * LW);
    float4 w4b = *(const float4*)(lbase + 4 * LW + 4);
    float4 w5a = *(const float4*)(lbase + 5 * LW);
    float4 w5b = *(const float4*)(lbase + 5 * LW + 4);

    float4 csA = add4(add4(add4(w0a, w1a), add4(w2a, w3a)), w4a);
    float4 csB = add4(add4(add4(w0b, w1b), add4(w2b, w3b)), w4b);

    const float4 p12a = max4(w1a, w2a), p12b = max4(w1b, w2b);
    const float4 p34a = max4(w3a, w4a), p34b = max4(w3b, w4b);
    const float4 cm0a = max34(w0a, p12a, p34a);
    const float4 cm0b = max34(w0b, p12b, p34b);

    float* __restrict__ orow =
        out + (size_t)plane * (HW * HW) + (size_t)(ty0 + r0) * HW + (tx0 + 4 * tx);

    proc_row(w0a,w0b, w1a,w1b, w2a,w2b, w3a,w3b, w4a,w4b,
             cm0a, cm0b, csA, csB, bp, c04b, inv_bp, lam, orow);

    csA = add4(csA, sub4(w5a, w0a));
    csB = add4(csB, sub4(w5b, w0b));
    const float4 cm1a = max34(p12a, p34a, w5a);
    const float4 cm1b = max34(p12b, p34b, w5b);

    proc_row(w1a,w1b, w2a,w2b, w3a,w3b, w4a,w4b, w5a,w5b,
             cm1a, cm1b, csA, csB, bp, c04b, inv_bp, lam, orow + HW);
}

extern "C" void kernel_launch(void* const* d_in, const int* in_sizes, int n_in,
                              void* d_out, int out_size, void* d_ws, size_t ws_size,
                              hipStream_t stream) {
    const float* x        = (const float*)d_in[0];
    const float* mix      = (const float*)d_in[1];
    const float* beta_raw = (const float*)d_in[2];
    float* out            = (float*)d_out;

    const int planes = in_sizes[0] / (HW * HW);                 // 128
    const int C      = in_sizes[1];                             // 32
    const int tiles_per_plane = (HW / TW) * (HW / TH);          // 64
    const int grid = planes * tiles_per_plane;                  // 8192

    maxmedian_kernel<<<grid, 128, 0, stream>>>(x, mix, beta_raw, out, C);
}